// Round 1
// baseline (1908.042 us; speedup 1.0000x reference)
//
#include <hip/hip_runtime.h>
#include <hip/hip_bf16.h>

// Problem constants
#define B   16
#define H   24
#define W   96
#define C   1024
#define HID 256
#define V   5000
#define EMB 256
#define HW  (H*W)          // 2304
#define BN_EPS 1e-5f

// d_out layout (floats): output[B*V] | hidden[B*HID] | alpha[B*HW] | att_sum[B*HW]
#define OUT0 0
#define OUT1 (B*V)                 // 80000
#define OUT2 (OUT1 + B*HID)        // 84096
#define OUT3 (OUT2 + B*HW)         // 120960

// ws layout (floats)
#define WS_ET   0                          // B*HW*256 NHWC et
#define WS_WT   (WS_ET + B*HW*256)         // 9*256*256 transposed conv weights
#define WS_E    (WS_WT + 9*256*256)        // B*HW
#define WS_ST1  (WS_E + B*HW)              // B*256
#define WS_CT   (WS_ST1 + B*HID)           // B*1024
#define WS_PRE  (WS_CT + B*C)              // B*128

// ---------------- K1: emb gather + GRU1 + fc1 -> st1 ----------------
__global__ __launch_bounds__(256) void k_st1(
    const int* y, const float* emb_table, const float* h0,
    const float* wi, const float* wh, const float* bi, const float* bh,
    const float* fc1_w, const float* fc1_b, float* st1_out)
{
    int b = blockIdx.x, t = threadIdx.x;
    __shared__ float emb_l[256], h_l[256], g_l[256];
    emb_l[t] = emb_table[y[b]*EMB + t];
    h_l[t]   = h0[b*HID + t];
    __syncthreads();
    float ir = bi[t], iz = bi[256+t], in_ = bi[512+t];
    float hr = bh[t], hz = bh[256+t], hn  = bh[512+t];
    for (int k = 0; k < 256; ++k) {
        float e = emb_l[k], h = h_l[k];
        ir += e*wi[k*768+t]; iz += e*wi[k*768+256+t]; in_ += e*wi[k*768+512+t];
        hr += h*wh[k*768+t]; hz += h*wh[k*768+256+t]; hn  += h*wh[k*768+512+t];
    }
    float r = 1.f/(1.f+__expf(-(ir+hr)));
    float z = 1.f/(1.f+__expf(-(iz+hz)));
    float n = tanhf(in_ + r*hn);
    float s = (1.f - z)*n + z*h_l[t];
    g_l[t] = s;
    __syncthreads();
    float acc = fc1_b[t];
    for (int k = 0; k < 256; ++k) acc += g_l[k]*fc1_w[k*256+t];
    st1_out[b*256+t] = acc;
}

// ---------------- K2: 1-ch 3x3 conv on alpha_t + attention_sum -> att_sum ----------------
__global__ __launch_bounds__(256) void k_attsum(
    const float* att_in, const float* alpha_t, const float* cw, const float* cb,
    float* att_out)
{
    int i = blockIdx.x*256 + threadIdx.x;   // B*HW = 36864
    int w = i % W; int h = (i / W) % H; int b = i / HW;
    float s = cb[0];
    #pragma unroll
    for (int kh = 0; kh < 3; ++kh) {
        int r = h + kh - 1; if (r < 0 || r >= H) continue;
        #pragma unroll
        for (int kw = 0; kw < 3; ++kw) {
            int c = w + kw - 1; if (c < 0 || c >= W) continue;
            s += alpha_t[(b*H + r)*W + c]*cw[kh*3+kw];
        }
    }
    att_out[i] = att_in[i] + s;
}

// ---------------- K3: transpose conv_tan_w OIHW(256,256,3,3) -> [khw][c][o] ----------------
__global__ __launch_bounds__(256) void k_wt(const float* src, float* dst)
{
    int idx = blockIdx.x*256 + threadIdx.x;     // 9*256*256 = 589824
    int o = idx & 255; int c = (idx >> 8) & 255; int khw = idx >> 16;
    dst[(khw*256 + c)*256 + o] = src[(o*256 + c)*9 + khw];
}

// ---------------- K4: et[b,h,w,c] = img1 + ua_b + st1 + att_sum*uf_w + uf_b (NHWC) ----------------
__global__ __launch_bounds__(256) void k_et(
    const float* img, const float* ua_w, const float* ua_b,
    const float* st1, const float* att_sum, const float* uf_w, const float* uf_b,
    float* et)
{
    int b = blockIdx.z, h = blockIdx.y, w0 = blockIdx.x*24;
    int t = threadIdx.x;                     // t = output channel d
    __shared__ float a_l[8*24];
    float acc[24];
    #pragma unroll
    for (int j = 0; j < 24; ++j) acc[j] = 0.f;
    for (int c0 = 0; c0 < C; c0 += 8) {
        __syncthreads();
        if (t < 192) {
            int cc = t/24, j = t%24;
            a_l[t] = img[((b*C + c0 + cc)*H + h)*W + w0 + j];
        }
        __syncthreads();
        #pragma unroll
        for (int cc = 0; cc < 8; ++cc) {
            float wv = ua_w[(c0+cc)*256 + t];
            float2 ev[12];
            #pragma unroll
            for (int x = 0; x < 12; ++x) ev[x] = *(const float2*)&a_l[cc*24 + 2*x];
            #pragma unroll
            for (int x = 0; x < 12; ++x) {
                acc[2*x]   += ev[x].x*wv;
                acc[2*x+1] += ev[x].y*wv;
            }
        }
    }
    float s1 = st1[b*256 + t] + ua_b[t];
    float ufw = uf_w[t], ufb = uf_b[t];
    #pragma unroll 4
    for (int j = 0; j < 24; ++j) {
        float att = att_sum[(b*H + h)*W + w0 + j];
        et[((b*H + h)*W + w0 + j)*256 + t] = acc[j] + s1 + att*ufw + ufb;
    }
}

// ---------------- K5: conv_tan(3x3,256->256) + BN + tanh + dot(v_w) -> e[b,h,w] ----------------
// Masked positions of e are never used downstream (exp(e)*mask), so mask is skipped.
#define WT 16
__global__ __launch_bounds__(256) void k_conv(
    const float* et, const float* wt, const float* cb,
    const float* bn_g, const float* bn_b, const float* bn_m, const float* bn_v,
    const float* v_w, const float* v_b, float* e_out)
{
    int b = blockIdx.z, h = blockIdx.y, w0 = blockIdx.x*WT;
    int o = threadIdx.x;                     // output channel
    __shared__ float row_l[18*256];          // also reused for the reduction
    float acc[WT];
    #pragma unroll
    for (int j = 0; j < WT; ++j) acc[j] = 0.f;

    for (int kh = 0; kh < 3; ++kh) {
        int r = h + kh - 1;
        if (r < 0 || r >= H) continue;       // block-uniform
        __syncthreads();
        #pragma unroll
        for (int x = 0; x < 18; ++x) {
            int col = w0 - 1 + x;
            row_l[x*256 + o] = (col >= 0 && col < W) ? et[((b*H + r)*W + col)*256 + o] : 0.f;
        }
        __syncthreads();
        for (int c = 0; c < 256; c += 2) {
            float2 ev[18];
            #pragma unroll
            for (int x = 0; x < 18; ++x) ev[x] = *(const float2*)&row_l[x*256 + c];
            #pragma unroll
            for (int kw = 0; kw < 3; ++kw) {
                float wv0 = wt[((kh*3+kw)*256 + c  )*256 + o];
                float wv1 = wt[((kh*3+kw)*256 + c+1)*256 + o];
                #pragma unroll
                for (int j = 0; j < WT; ++j)
                    acc[j] += ev[j+kw].x*wv0 + ev[j+kw].y*wv1;
            }
        }
    }

    // epilogue: bias, BN, tanh, *v_w, reduce over o
    float inv = bn_g[o]*rsqrtf(bn_v[o] + BN_EPS);
    float mean = bn_m[o], beta = bn_b[o], bias = cb[o], vw = v_w[o];
    __syncthreads();
    #pragma unroll
    for (int j = 0; j < WT; ++j) {
        float x = (acc[j] + bias - mean)*inv + beta;
        row_l[j*256 + o] = tanhf(x)*vw;
    }
    __syncthreads();
    for (int s = 128; s > 0; s >>= 1) {
        if (o < s) {
            #pragma unroll
            for (int j = 0; j < WT; ++j) row_l[j*256 + o] += row_l[j*256 + o + s];
        }
        __syncthreads();
    }
    if (o < WT) e_out[(b*H + h)*W + w0 + o] = row_l[o*256] + v_b[0];
}

// ---------------- K6: masked softmax over (h,w) -> alpha ----------------
__global__ __launch_bounds__(256) void k_softmax(
    const float* e, const int* h_mask, const int* w_mask, float* alpha_out)
{
    int b = blockIdx.x, t = threadIdx.x;
    int hm = h_mask[b], wm = w_mask[b];
    __shared__ float red[256];
    float vals[9];
    float loc = 0.f;
    #pragma unroll
    for (int i = 0; i < 9; ++i) {
        int hw = t + i*256;
        int hh = hw / W, ww = hw % W;
        float v = 0.f;
        if (hh < hm && ww < wm) v = __expf(e[b*HW + hw]);
        vals[i] = v; loc += v;
    }
    red[t] = loc; __syncthreads();
    for (int s = 128; s > 0; s >>= 1) { if (t < s) red[t] += red[t+s]; __syncthreads(); }
    float inv = 1.f/(red[0] + 1e-8f);
    #pragma unroll
    for (int i = 0; i < 9; ++i) alpha_out[b*HW + t + i*256] = vals[i]*inv;
}

// ---------------- K7: ct[b,c] = sum_hw alpha[b,hw]*img[b,c,hw] ----------------
__global__ __launch_bounds__(256) void k_ct(
    const float* alpha, const float* img, float* ct)
{
    int c = blockIdx.x, b = blockIdx.y, t = threadIdx.x;
    const float* ip = img + (size_t)(b*C + c)*HW;
    const float* ap = alpha + b*HW;
    float s = 0.f;
    for (int i = t; i < HW; i += 256) s += ap[i]*ip[i];
    __shared__ float red[256];
    red[t] = s; __syncthreads();
    for (int st = 128; st > 0; st >>= 1) { if (t < st) red[t] += red[t+st]; __syncthreads(); }
    if (t == 0) ct[b*C + c] = red[0];
}

// ---------------- K8: GRU2 + pre (fc2 + emb2 + wc) ----------------
__global__ __launch_bounds__(256) void k_gru2(
    const float* ct, const float* st1, const int* y, const float* emb_table,
    const float* wi, const float* wh, const float* bi, const float* bh,
    const float* fc2_w, const float* fc2_b, const float* emb2_w, const float* emb2_b,
    const float* wc_w, const float* wc_b,
    float* hidden_out, float* pre_out)
{
    int b = blockIdx.x, t = threadIdx.x;
    __shared__ float ct_l[1024], s1_l[256], emb_l[256], st_l[256];
    for (int i = t; i < 1024; i += 256) ct_l[i] = ct[b*C + i];
    s1_l[t]  = st1[b*256 + t];
    emb_l[t] = emb_table[y[b]*EMB + t];
    __syncthreads();
    float ir = bi[t], iz = bi[256+t], in_ = bi[512+t];
    for (int k = 0; k < 1024; ++k) {
        float cv = ct_l[k];
        ir += cv*wi[k*768+t]; iz += cv*wi[k*768+256+t]; in_ += cv*wi[k*768+512+t];
    }
    float hr = bh[t], hz = bh[256+t], hn = bh[512+t];
    for (int k = 0; k < 256; ++k) {
        float hv = s1_l[k];
        hr += hv*wh[k*768+t]; hz += hv*wh[k*768+256+t]; hn += hv*wh[k*768+512+t];
    }
    float r = 1.f/(1.f+__expf(-(ir+hr)));
    float z = 1.f/(1.f+__expf(-(iz+hz)));
    float n = tanhf(in_ + r*hn);
    float s = (1.f - z)*n + z*s1_l[t];
    hidden_out[b*HID + t] = s;
    st_l[t] = s;
    __syncthreads();
    if (t < 128) {
        float acc = fc2_b[t] + emb2_b[t] + wc_b[t];
        for (int k = 0; k < 256; ++k) acc += st_l[k]*fc2_w[k*128+t] + emb_l[k]*emb2_w[k*128+t];
        for (int k = 0; k < 1024; ++k) acc += ct_l[k]*wc_w[k*128+t];
        pre_out[b*128 + t] = acc;
    }
}

// ---------------- K9: logits = pre @ out_w + out_b; log_softmax ----------------
__global__ __launch_bounds__(1024) void k_out(
    const float* pre, const float* out_w, const float* out_b, float* out)
{
    int b = blockIdx.x, t = threadIdx.x;   // 1024 threads
    __shared__ float pre_l[128];
    __shared__ float red[1024];
    if (t < 128) pre_l[t] = pre[b*128 + t];
    __syncthreads();
    float lg[5];
    float mx = -1e30f;
    #pragma unroll
    for (int i = 0; i < 5; ++i) {
        int j = t + i*1024;
        float a = -1e30f;
        if (j < V) {
            a = out_b[j];
            for (int k = 0; k < 128; ++k) a += pre_l[k]*out_w[k*V + j];
        }
        lg[i] = a; mx = fmaxf(mx, a);
    }
    red[t] = mx; __syncthreads();
    for (int s = 512; s > 0; s >>= 1) { if (t < s) red[t] = fmaxf(red[t], red[t+s]); __syncthreads(); }
    float gmax = red[0]; __syncthreads();
    float se = 0.f;
    #pragma unroll
    for (int i = 0; i < 5; ++i) { int j = t + i*1024; if (j < V) se += __expf(lg[i] - gmax); }
    red[t] = se; __syncthreads();
    for (int s = 512; s > 0; s >>= 1) { if (t < s) red[t] += red[t+s]; __syncthreads(); }
    float lse = logf(red[0]);
    #pragma unroll
    for (int i = 0; i < 5; ++i) { int j = t + i*1024; if (j < V) out[b*V + j] = lg[i] - gmax - lse; }
}

extern "C" void kernel_launch(void* const* d_in, const int* in_sizes, int n_in,
                              void* d_out, int out_size, void* d_ws, size_t ws_size,
                              hipStream_t stream)
{
    const int*   input_y      = (const int*)  d_in[0];
    const float* input_hidden = (const float*)d_in[1];
    const float* img          = (const float*)d_in[2];
    const float* attention    = (const float*)d_in[4];
    const float* alpha_t      = (const float*)d_in[5];
    const int*   h_mask       = (const int*)  d_in[8];
    const int*   w_mask       = (const int*)  d_in[9];
    const float* emb_table    = (const float*)d_in[10];
    const float* gru1_wi      = (const float*)d_in[11];
    const float* gru1_wh      = (const float*)d_in[12];
    const float* gru1_bi      = (const float*)d_in[13];
    const float* gru1_bh      = (const float*)d_in[14];
    const float* fc1_w        = (const float*)d_in[15];
    const float* fc1_b        = (const float*)d_in[16];
    const float* gru2_wi      = (const float*)d_in[17];
    const float* gru2_wh      = (const float*)d_in[18];
    const float* gru2_bi      = (const float*)d_in[19];
    const float* gru2_bh      = (const float*)d_in[20];
    const float* out_w        = (const float*)d_in[21];
    const float* out_b        = (const float*)d_in[22];
    const float* emb2_w       = (const float*)d_in[23];
    const float* emb2_b       = (const float*)d_in[24];
    const float* conv1_w      = (const float*)d_in[25];
    const float* conv1_b      = (const float*)d_in[26];
    const float* conv_tan_w   = (const float*)d_in[27];
    const float* conv_tan_b   = (const float*)d_in[28];
    const float* fc2_w        = (const float*)d_in[29];
    const float* fc2_b        = (const float*)d_in[30];
    const float* ua_w         = (const float*)d_in[31];
    const float* ua_b         = (const float*)d_in[32];
    const float* uf_w         = (const float*)d_in[33];
    const float* uf_b         = (const float*)d_in[34];
    const float* v_w          = (const float*)d_in[35];
    const float* v_b          = (const float*)d_in[36];
    const float* wc_w         = (const float*)d_in[37];
    const float* wc_b         = (const float*)d_in[38];
    const float* bn1_gamma    = (const float*)d_in[39];
    const float* bn1_beta     = (const float*)d_in[40];
    const float* bn1_mean     = (const float*)d_in[41];
    const float* bn1_var      = (const float*)d_in[42];

    float* out   = (float*)d_out;
    float* ws    = (float*)d_ws;
    float* et    = ws + WS_ET;
    float* wt    = ws + WS_WT;
    float* e_buf = ws + WS_E;
    float* st1   = ws + WS_ST1;
    float* ct    = ws + WS_CT;
    float* pre   = ws + WS_PRE;

    float* out_logits = out + OUT0;
    float* out_hidden = out + OUT1;
    float* out_alpha  = out + OUT2;
    float* out_attsum = out + OUT3;

    k_st1<<<B, 256, 0, stream>>>(input_y, emb_table, input_hidden,
                                 gru1_wi, gru1_wh, gru1_bi, gru1_bh,
                                 fc1_w, fc1_b, st1);
    k_attsum<<<(B*HW)/256, 256, 0, stream>>>(attention, alpha_t, conv1_w, conv1_b, out_attsum);
    k_wt<<<(9*256*256)/256, 256, 0, stream>>>(conv_tan_w, wt);
    k_et<<<dim3(W/24, H, B), 256, 0, stream>>>(img, ua_w, ua_b, st1, out_attsum,
                                               uf_w, uf_b, et);
    k_conv<<<dim3(W/WT, H, B), 256, 0, stream>>>(et, wt, conv_tan_b,
                                                 bn1_gamma, bn1_beta, bn1_mean, bn1_var,
                                                 v_w, v_b, e_buf);
    k_softmax<<<B, 256, 0, stream>>>(e_buf, h_mask, w_mask, out_alpha);
    k_ct<<<dim3(C, B), 256, 0, stream>>>(out_alpha, img, ct);
    k_gru2<<<B, 256, 0, stream>>>(ct, st1, input_y, emb_table,
                                  gru2_wi, gru2_wh, gru2_bi, gru2_bh,
                                  fc2_w, fc2_b, emb2_w, emb2_b, wc_w, wc_b,
                                  out_hidden, pre);
    k_out<<<B, 1024, 0, stream>>>(pre, out_w, out_b, out_logits);
}

// Round 2
// 943.820 us; speedup vs baseline: 2.0216x; 2.0216x over previous
//
#include <hip/hip_runtime.h>
#include <hip/hip_bf16.h>

// Problem constants
#define B   16
#define H   24
#define W   96
#define C   1024
#define HID 256
#define V   5000
#define EMB 256
#define HW  (H*W)          // 2304
#define BN_EPS 1e-5f
#define H2  (H+2)          // 26 (halo-padded)
#define W2  (W+2)          // 98

// d_out layout (floats): output[B*V] | hidden[B*HID] | alpha[B*HW] | att_sum[B*HW]
#define OUT0 0
#define OUT1 (B*V)
#define OUT2 (OUT1 + B*HID)
#define OUT3 (OUT2 + B*HW)

// ws layout (bytes, 256-aligned)
#define WSB_ETP 0                      // B*H2*W2*256 bf16 = 20,873,216
#define WSB_WTB 20873216               // 9*256*256 bf16   =  1,179,648
#define WSB_UAT 22052864               // 256*1024 bf16    =    524,288
#define WSB_E   22577152               // B*HW f32         =    147,456
#define WSB_ST1 22724608               // B*256 f32
#define WSB_CT  22740992               // B*1024 f32
#define WSB_PRE 22806528               // B*128 f32

typedef __attribute__((ext_vector_type(8))) short short8;
typedef __attribute__((ext_vector_type(4))) float f32x4;

__device__ inline unsigned short f2bf(float f) {
    union { float f; unsigned int u; } v; v.f = f;
    unsigned int r = v.u + 0x7fffu + ((v.u >> 16) & 1u);   // RNE
    return (unsigned short)(r >> 16);
}

// ---------------- K1: emb gather + GRU1 + fc1 -> st1 ----------------
__global__ __launch_bounds__(256) void k_st1(
    const int* y, const float* emb_table, const float* h0,
    const float* wi, const float* wh, const float* bi, const float* bh,
    const float* fc1_w, const float* fc1_b, float* st1_out)
{
    int b = blockIdx.x, t = threadIdx.x;
    __shared__ float emb_l[256], h_l[256], g_l[256];
    emb_l[t] = emb_table[y[b]*EMB + t];
    h_l[t]   = h0[b*HID + t];
    __syncthreads();
    float ir = bi[t], iz = bi[256+t], in_ = bi[512+t];
    float hr = bh[t], hz = bh[256+t], hn  = bh[512+t];
    for (int k = 0; k < 256; ++k) {
        float e = emb_l[k], h = h_l[k];
        ir += e*wi[k*768+t]; iz += e*wi[k*768+256+t]; in_ += e*wi[k*768+512+t];
        hr += h*wh[k*768+t]; hz += h*wh[k*768+256+t]; hn  += h*wh[k*768+512+t];
    }
    float r = 1.f/(1.f+__expf(-(ir+hr)));
    float z = 1.f/(1.f+__expf(-(iz+hz)));
    float n = tanhf(in_ + r*hn);
    float s = (1.f - z)*n + z*h_l[t];
    g_l[t] = s;
    __syncthreads();
    float acc = fc1_b[t];
    for (int k = 0; k < 256; ++k) acc += g_l[k]*fc1_w[k*256+t];
    st1_out[b*256+t] = acc;
}

// ---------------- K2: 1-ch 3x3 conv on alpha_t + attention_sum -> att_sum ----------------
__global__ __launch_bounds__(256) void k_attsum(
    const float* att_in, const float* alpha_t, const float* cw, const float* cb,
    float* att_out)
{
    int i = blockIdx.x*256 + threadIdx.x;
    int w = i % W; int h = (i / W) % H; int b = i / HW;
    float s = cb[0];
    #pragma unroll
    for (int kh = 0; kh < 3; ++kh) {
        int r = h + kh - 1; if (r < 0 || r >= H) continue;
        #pragma unroll
        for (int kw = 0; kw < 3; ++kw) {
            int c = w + kw - 1; if (c < 0 || c >= W) continue;
            s += alpha_t[(b*H + r)*W + c]*cw[kh*3+kw];
        }
    }
    att_out[i] = att_in[i] + s;
}

// ---------------- K3: conv_tan_w OIHW -> bf16 [khw][o][c] ----------------
__global__ __launch_bounds__(256) void k_wtb(const float* src, unsigned short* dst)
{
    int idx = blockIdx.x*256 + threadIdx.x;     // 9*256*256
    int c = idx & 255; int o = (idx >> 8) & 255; int khw = idx >> 16;
    dst[(khw*256 + o)*256 + c] = f2bf(src[(o*256 + c)*9 + khw]);
}

// ---------------- K3b: ua_w [c][d] -> bf16 [d][c] ----------------
__global__ __launch_bounds__(256) void k_uat(const float* src, unsigned short* dst)
{
    int idx = blockIdx.x*256 + threadIdx.x;     // 256*1024
    int c = idx & 1023; int d = idx >> 10;
    dst[d*1024 + c] = f2bf(src[c*256 + d]);
}

// ---------------- K3c: zero et_p (incl. halo) ----------------
__global__ __launch_bounds__(256) void k_zero(int4* p)
{
    p[blockIdx.x*256 + threadIdx.x] = make_int4(0,0,0,0);
}

// ---------------- K4: MFMA GEMM et[m][d] = imgT @ ua_w + fused epilogue -> bf16 NHWC (halo-padded) ----------------
// M-tile = 32 w-positions in row (b,h); N = 256; K = 1024, BK = 64 via LDS transpose staging.
__global__ __launch_bounds__(256) void k_et(
    const float* img, const unsigned short* uat, const float* ua_b,
    const float* st1, const float* att_sum, const float* uf_w, const float* uf_b,
    unsigned short* et_p)
{
    int b = blockIdx.z, h = blockIdx.y, w0 = blockIdx.x*32;
    int t = threadIdx.x;
    int wv = t >> 6, lane = t & 63, q = lane >> 4, ln = lane & 15;
    __shared__ __align__(16) unsigned short lds_a[32*72];   // [m][k] stride 72

    f32x4 acc[8];                                           // [mf*4 + j]
    #pragma unroll
    for (int i = 0; i < 8; ++i) acc[i] = (f32x4){0.f,0.f,0.f,0.f};

    int stg_m = t & 31;                 // position within tile
    int stg_c = t >> 5;                 // base cc-pair 0..7
    int hwb = h*W + w0 + stg_m;
    int n0 = wv*64;

    for (int c0 = 0; c0 < 1024; c0 += 64) {
        __syncthreads();
        #pragma unroll
        for (int i = 0; i < 4; ++i) {
            int ccp = stg_c + 8*i;                          // 0..31, pair of channels
            float f0 = img[(b*C + c0 + 2*ccp    )*HW + hwb];
            float f1 = img[(b*C + c0 + 2*ccp + 1)*HW + hwb];
            ushort2 u; u.x = f2bf(f0); u.y = f2bf(f1);
            *(ushort2*)&lds_a[stg_m*72 + 2*ccp] = u;
        }
        __syncthreads();
        #pragma unroll
        for (int k0 = 0; k0 < 64; k0 += 32) {
            short8 a0 = *(const short8*)&lds_a[(ln     )*72 + k0 + q*8];
            short8 a1 = *(const short8*)&lds_a[(ln + 16)*72 + k0 + q*8];
            #pragma unroll
            for (int j = 0; j < 4; ++j) {
                short8 bf = *(const short8*)&uat[(n0 + j*16 + ln)*1024 + c0 + k0 + q*8];
                acc[0*4+j] = __builtin_amdgcn_mfma_f32_16x16x32_bf16(a0, bf, acc[0*4+j], 0, 0, 0);
                acc[1*4+j] = __builtin_amdgcn_mfma_f32_16x16x32_bf16(a1, bf, acc[1*4+j], 0, 0, 0);
            }
        }
    }

    // epilogue: + st1 + ua_b + att*uf_w + uf_b, store bf16 NHWC halo-padded
    float att_m[8];
    #pragma unroll
    for (int mf = 0; mf < 2; ++mf)
        #pragma unroll
        for (int r = 0; r < 4; ++r)
            att_m[mf*4+r] = att_sum[(b*H + h)*W + w0 + mf*16 + q*4 + r];
    #pragma unroll
    for (int j = 0; j < 4; ++j) {
        int n = n0 + j*16 + ln;
        float s1 = st1[b*256 + n] + ua_b[n];
        float ufw = uf_w[n], ufb = uf_b[n];
        #pragma unroll
        for (int mf = 0; mf < 2; ++mf)
            #pragma unroll
            for (int r = 0; r < 4; ++r) {
                int m = mf*16 + q*4 + r;
                float v = acc[mf*4+j][r] + s1 + att_m[mf*4+r]*ufw + ufb;
                et_p[((b*H2 + h + 1)*W2 + (w0 + 1 + m))*256 + n] = f2bf(v);
            }
    }
}

// ---------------- K5: MFMA conv(3x3,256->256) + BN + tanh + v-dot -> e[b,h,w] ----------------
// A = halo-padded bf16 et (global, L1/L2); B = wtb [khw][o][c]; K = 9*256.
__global__ __launch_bounds__(256) void k_conv(
    const unsigned short* et_p, const unsigned short* wtb, const float* cb,
    const float* bn_g, const float* bn_b, const float* bn_m, const float* bn_v,
    const float* v_w, const float* v_b, float* e_out)
{
    int b = blockIdx.z, h = blockIdx.y, w0 = blockIdx.x*32;
    int t = threadIdx.x;
    int wv = t >> 6, lane = t & 63, q = lane >> 4, ln = lane & 15;
    int n0 = wv*64;
    __shared__ float lds_red[4][32];

    f32x4 acc[8];                                           // [mf*4 + j]
    #pragma unroll
    for (int i = 0; i < 8; ++i) acc[i] = (f32x4){0.f,0.f,0.f,0.f};

    #pragma unroll
    for (int kh = 0; kh < 3; ++kh) {
        #pragma unroll
        for (int kw = 0; kw < 3; ++kw) {
            const unsigned short* arow = et_p + ((size_t)((b*H2 + h + kh)*W2 + (w0 + kw + ln)))*256 + q*8;
            const unsigned short* brow = wtb + ((size_t)((kh*3 + kw)*256 + n0 + ln))*256 + q*8;
            for (int c0 = 0; c0 < 256; c0 += 32) {
                short8 a0 = *(const short8*)(arow + c0);
                short8 a1 = *(const short8*)(arow + 16*256 + c0);
                #pragma unroll
                for (int j = 0; j < 4; ++j) {
                    short8 bf = *(const short8*)(brow + j*16*256 + c0);
                    acc[0*4+j] = __builtin_amdgcn_mfma_f32_16x16x32_bf16(a0, bf, acc[0*4+j], 0, 0, 0);
                    acc[1*4+j] = __builtin_amdgcn_mfma_f32_16x16x32_bf16(a1, bf, acc[1*4+j], 0, 0, 0);
                }
            }
        }
    }

    // epilogue: bias + BN + tanh + *v_w, reduce over o (=n)
    float psum[8];                                          // [mf*4 + r]
    #pragma unroll
    for (int i = 0; i < 8; ++i) psum[i] = 0.f;
    #pragma unroll
    for (int j = 0; j < 4; ++j) {
        int o = n0 + j*16 + ln;
        float inv  = bn_g[o]*rsqrtf(bn_v[o] + BN_EPS);
        float mean = bn_m[o], beta = bn_b[o], bias = cb[o], vw = v_w[o];
        #pragma unroll
        for (int mf = 0; mf < 2; ++mf)
            #pragma unroll
            for (int r = 0; r < 4; ++r) {
                float x = (acc[mf*4+j][r] + bias - mean)*inv + beta;
                x = fminf(fmaxf(x, -15.f), 15.f);
                float ex = __expf(2.f*x);
                psum[mf*4+r] += ((ex - 1.f)/(ex + 1.f))*vw;
            }
    }
    #pragma unroll
    for (int s = 1; s < 16; s <<= 1)
        #pragma unroll
        for (int i = 0; i < 8; ++i) psum[i] += __shfl_xor(psum[i], s);
    if (ln == 0) {
        #pragma unroll
        for (int mf = 0; mf < 2; ++mf)
            #pragma unroll
            for (int r = 0; r < 4; ++r)
                lds_red[wv][mf*16 + q*4 + r] = psum[mf*4+r];
    }
    __syncthreads();
    if (t < 32)
        e_out[(b*H + h)*W + w0 + t] =
            lds_red[0][t] + lds_red[1][t] + lds_red[2][t] + lds_red[3][t] + v_b[0];
}

// ---------------- K6: masked softmax over (h,w) -> alpha ----------------
__global__ __launch_bounds__(256) void k_softmax(
    const float* e, const int* h_mask, const int* w_mask, float* alpha_out)
{
    int b = blockIdx.x, t = threadIdx.x;
    int hm = h_mask[b], wm = w_mask[b];
    __shared__ float red[256];
    float vals[9];
    float loc = 0.f;
    #pragma unroll
    for (int i = 0; i < 9; ++i) {
        int hw = t + i*256;
        int hh = hw / W, ww = hw % W;
        float v = 0.f;
        if (hh < hm && ww < wm) v = __expf(e[b*HW + hw]);
        vals[i] = v; loc += v;
    }
    red[t] = loc; __syncthreads();
    for (int s = 128; s > 0; s >>= 1) { if (t < s) red[t] += red[t+s]; __syncthreads(); }
    float inv = 1.f/(red[0] + 1e-8f);
    #pragma unroll
    for (int i = 0; i < 9; ++i) alpha_out[b*HW + t + i*256] = vals[i]*inv;
}

// ---------------- K7: ct[b,c] = sum_hw alpha[b,hw]*img[b,c,hw] ----------------
__global__ __launch_bounds__(256) void k_ct(
    const float* alpha, const float* img, float* ct)
{
    int c = blockIdx.x, b = blockIdx.y, t = threadIdx.x;
    const float* ip = img + (size_t)(b*C + c)*HW;
    const float* ap = alpha + b*HW;
    float s = 0.f;
    for (int i = t; i < HW; i += 256) s += ap[i]*ip[i];
    __shared__ float red[256];
    red[t] = s; __syncthreads();
    for (int st = 128; st > 0; st >>= 1) { if (t < st) red[t] += red[t+st]; __syncthreads(); }
    if (t == 0) ct[b*C + c] = red[0];
}

// ---------------- K8: GRU2 + pre (fc2 + emb2 + wc) ----------------
__global__ __launch_bounds__(256) void k_gru2(
    const float* ct, const float* st1, const int* y, const float* emb_table,
    const float* wi, const float* wh, const float* bi, const float* bh,
    const float* fc2_w, const float* fc2_b, const float* emb2_w, const float* emb2_b,
    const float* wc_w, const float* wc_b,
    float* hidden_out, float* pre_out)
{
    int b = blockIdx.x, t = threadIdx.x;
    __shared__ float ct_l[1024], s1_l[256], emb_l[256], st_l[256];
    for (int i = t; i < 1024; i += 256) ct_l[i] = ct[b*C + i];
    s1_l[t]  = st1[b*256 + t];
    emb_l[t] = emb_table[y[b]*EMB + t];
    __syncthreads();
    float ir = bi[t], iz = bi[256+t], in_ = bi[512+t];
    for (int k = 0; k < 1024; ++k) {
        float cv = ct_l[k];
        ir += cv*wi[k*768+t]; iz += cv*wi[k*768+256+t]; in_ += cv*wi[k*768+512+t];
    }
    float hr = bh[t], hz = bh[256+t], hn = bh[512+t];
    for (int k = 0; k < 256; ++k) {
        float hv = s1_l[k];
        hr += hv*wh[k*768+t]; hz += hv*wh[k*768+256+t]; hn += hv*wh[k*768+512+t];
    }
    float r = 1.f/(1.f+__expf(-(ir+hr)));
    float z = 1.f/(1.f+__expf(-(iz+hz)));
    float n = tanhf(in_ + r*hn);
    float s = (1.f - z)*n + z*s1_l[t];
    hidden_out[b*HID + t] = s;
    st_l[t] = s;
    __syncthreads();
    if (t < 128) {
        float acc = fc2_b[t] + emb2_b[t] + wc_b[t];
        for (int k = 0; k < 256; ++k) acc += st_l[k]*fc2_w[k*128+t] + emb_l[k]*emb2_w[k*128+t];
        for (int k = 0; k < 1024; ++k) acc += ct_l[k]*wc_w[k*128+t];
        pre_out[b*128 + t] = acc;
    }
}

// ---------------- K9: logits = pre @ out_w + out_b; log_softmax ----------------
__global__ __launch_bounds__(1024) void k_out(
    const float* pre, const float* out_w, const float* out_b, float* out)
{
    int b = blockIdx.x, t = threadIdx.x;
    __shared__ float pre_l[128];
    __shared__ float red[1024];
    if (t < 128) pre_l[t] = pre[b*128 + t];
    __syncthreads();
    float lg[5];
    float mx = -1e30f;
    #pragma unroll
    for (int i = 0; i < 5; ++i) {
        int j = t + i*1024;
        float a = -1e30f;
        if (j < V) {
            a = out_b[j];
            for (int k = 0; k < 128; ++k) a += pre_l[k]*out_w[k*V + j];
        }
        lg[i] = a; mx = fmaxf(mx, a);
    }
    red[t] = mx; __syncthreads();
    for (int s = 512; s > 0; s >>= 1) { if (t < s) red[t] = fmaxf(red[t], red[t+s]); __syncthreads(); }
    float gmax = red[0]; __syncthreads();
    float se = 0.f;
    #pragma unroll
    for (int i = 0; i < 5; ++i) { int j = t + i*1024; if (j < V) se += __expf(lg[i] - gmax); }
    red[t] = se; __syncthreads();
    for (int s = 512; s > 0; s >>= 1) { if (t < s) red[t] += red[t+s]; __syncthreads(); }
    float lse = logf(red[0]);
    #pragma unroll
    for (int i = 0; i < 5; ++i) { int j = t + i*1024; if (j < V) out[b*V + j] = lg[i] - gmax - lse; }
}

extern "C" void kernel_launch(void* const* d_in, const int* in_sizes, int n_in,
                              void* d_out, int out_size, void* d_ws, size_t ws_size,
                              hipStream_t stream)
{
    const int*   input_y      = (const int*)  d_in[0];
    const float* input_hidden = (const float*)d_in[1];
    const float* img          = (const float*)d_in[2];
    const float* attention    = (const float*)d_in[4];
    const float* alpha_t      = (const float*)d_in[5];
    const int*   h_mask       = (const int*)  d_in[8];
    const int*   w_mask       = (const int*)  d_in[9];
    const float* emb_table    = (const float*)d_in[10];
    const float* gru1_wi      = (const float*)d_in[11];
    const float* gru1_wh      = (const float*)d_in[12];
    const float* gru1_bi      = (const float*)d_in[13];
    const float* gru1_bh      = (const float*)d_in[14];
    const float* fc1_w        = (const float*)d_in[15];
    const float* fc1_b        = (const float*)d_in[16];
    const float* gru2_wi      = (const float*)d_in[17];
    const float* gru2_wh      = (const float*)d_in[18];
    const float* gru2_bi      = (const float*)d_in[19];
    const float* gru2_bh      = (const float*)d_in[20];
    const float* out_w        = (const float*)d_in[21];
    const float* out_b        = (const float*)d_in[22];
    const float* emb2_w       = (const float*)d_in[23];
    const float* emb2_b       = (const float*)d_in[24];
    const float* conv1_w      = (const float*)d_in[25];
    const float* conv1_b      = (const float*)d_in[26];
    const float* conv_tan_w   = (const float*)d_in[27];
    const float* conv_tan_b   = (const float*)d_in[28];
    const float* fc2_w        = (const float*)d_in[29];
    const float* fc2_b        = (const float*)d_in[30];
    const float* ua_w         = (const float*)d_in[31];
    const float* ua_b         = (const float*)d_in[32];
    const float* uf_w         = (const float*)d_in[33];
    const float* uf_b         = (const float*)d_in[34];
    const float* v_w          = (const float*)d_in[35];
    const float* v_b          = (const float*)d_in[36];
    const float* wc_w         = (const float*)d_in[37];
    const float* wc_b         = (const float*)d_in[38];
    const float* bn1_gamma    = (const float*)d_in[39];
    const float* bn1_beta     = (const float*)d_in[40];
    const float* bn1_mean     = (const float*)d_in[41];
    const float* bn1_var      = (const float*)d_in[42];

    float* out = (float*)d_out;
    char*  ws  = (char*)d_ws;
    unsigned short* et_p = (unsigned short*)(ws + WSB_ETP);
    unsigned short* wtb  = (unsigned short*)(ws + WSB_WTB);
    unsigned short* uat  = (unsigned short*)(ws + WSB_UAT);
    float* e_buf = (float*)(ws + WSB_E);
    float* st1   = (float*)(ws + WSB_ST1);
    float* ct    = (float*)(ws + WSB_CT);
    float* pre   = (float*)(ws + WSB_PRE);

    float* out_logits = out + OUT0;
    float* out_hidden = out + OUT1;
    float* out_alpha  = out + OUT2;
    float* out_attsum = out + OUT3;

    k_st1<<<B, 256, 0, stream>>>(input_y, emb_table, input_hidden,
                                 gru1_wi, gru1_wh, gru1_bi, gru1_bh,
                                 fc1_w, fc1_b, st1);
    k_attsum<<<(B*HW)/256, 256, 0, stream>>>(attention, alpha_t, conv1_w, conv1_b, out_attsum);
    k_wtb<<<(9*256*256)/256, 256, 0, stream>>>(conv_tan_w, wtb);
    k_uat<<<(256*1024)/256, 256, 0, stream>>>(ua_w, uat);
    k_zero<<<(B*H2*W2*256/8)/256, 256, 0, stream>>>((int4*)et_p);
    k_et<<<dim3(W/32, H, B), 256, 0, stream>>>(img, uat, ua_b, st1, out_attsum,
                                               uf_w, uf_b, et_p);
    k_conv<<<dim3(W/32, H, B), 256, 0, stream>>>(et_p, wtb, conv_tan_b,
                                                 bn1_gamma, bn1_beta, bn1_mean, bn1_var,
                                                 v_w, v_b, e_buf);
    k_softmax<<<B, 256, 0, stream>>>(e_buf, h_mask, w_mask, out_alpha);
    k_ct<<<dim3(C, B), 256, 0, stream>>>(out_alpha, img, ct);
    k_gru2<<<B, 256, 0, stream>>>(ct, st1, input_y, emb_table,
                                  gru2_wi, gru2_wh, gru2_bi, gru2_bh,
                                  fc2_w, fc2_b, emb2_w, emb2_b, wc_w, wc_b,
                                  out_hidden, pre);
    k_out<<<B, 1024, 0, stream>>>(pre, out_w, out_b, out_logits);
}

// Round 3
// 731.365 us; speedup vs baseline: 2.6089x; 1.2905x over previous
//
#include <hip/hip_runtime.h>
#include <hip/hip_bf16.h>

// Problem constants
#define B   16
#define H   24
#define W   96
#define C   1024
#define HID 256
#define V   5000
#define EMB 256
#define HW  (H*W)          // 2304
#define BN_EPS 1e-5f
#define H2  (H+2)          // 26 (halo-padded)
#define W2  (W+2)          // 98

// d_out layout (floats): output[B*V] | hidden[B*HID] | alpha[B*HW] | att_sum[B*HW]
#define OUT0 0
#define OUT1 (B*V)
#define OUT2 (OUT1 + B*HID)
#define OUT3 (OUT2 + B*HW)

// ws layout (bytes, 256-aligned)
#define WSB_ETP 0                      // B*H2*W2*256 bf16 = 20,873,216
#define WSB_WTB 20873216               // 9*256*256 bf16   =  1,179,648
#define WSB_UAT 22052864               // 256*1024 bf16    =    524,288
#define WSB_E   22577152               // B*HW f32         =    147,456
#define WSB_ST1 22724608               // B*256 f32
#define WSB_CT  22740992               // B*1024 f32
#define WSB_PRE 22806528               // B*128 f32

typedef __attribute__((ext_vector_type(8))) short short8;
typedef __attribute__((ext_vector_type(4))) float f32x4;

__device__ inline unsigned short f2bf(float f) {
    union { float f; unsigned int u; } v; v.f = f;
    unsigned int r = v.u + 0x7fffu + ((v.u >> 16) & 1u);   // RNE
    return (unsigned short)(r >> 16);
}

// ---------------- K1: emb gather + GRU1 + fc1 -> st1 ----------------
__global__ __launch_bounds__(256) void k_st1(
    const int* y, const float* emb_table, const float* h0,
    const float* wi, const float* wh, const float* bi, const float* bh,
    const float* fc1_w, const float* fc1_b, float* st1_out)
{
    int b = blockIdx.x, t = threadIdx.x;
    __shared__ float emb_l[256], h_l[256], g_l[256];
    emb_l[t] = emb_table[y[b]*EMB + t];
    h_l[t]   = h0[b*HID + t];
    __syncthreads();
    float ir = bi[t], iz = bi[256+t], in_ = bi[512+t];
    float hr = bh[t], hz = bh[256+t], hn  = bh[512+t];
    for (int k = 0; k < 256; ++k) {
        float e = emb_l[k], h = h_l[k];
        ir += e*wi[k*768+t]; iz += e*wi[k*768+256+t]; in_ += e*wi[k*768+512+t];
        hr += h*wh[k*768+t]; hz += h*wh[k*768+256+t]; hn  += h*wh[k*768+512+t];
    }
    float r = 1.f/(1.f+__expf(-(ir+hr)));
    float z = 1.f/(1.f+__expf(-(iz+hz)));
    float n = tanhf(in_ + r*hn);
    float s = (1.f - z)*n + z*h_l[t];
    g_l[t] = s;
    __syncthreads();
    float acc = fc1_b[t];
    for (int k = 0; k < 256; ++k) acc += g_l[k]*fc1_w[k*256+t];
    st1_out[b*256+t] = acc;
}

// ---------------- K2: 1-ch 3x3 conv on alpha_t + attention_sum -> att_sum ----------------
__global__ __launch_bounds__(256) void k_attsum(
    const float* att_in, const float* alpha_t, const float* cw, const float* cb,
    float* att_out)
{
    int i = blockIdx.x*256 + threadIdx.x;
    int w = i % W; int h = (i / W) % H; int b = i / HW;
    float s = cb[0];
    #pragma unroll
    for (int kh = 0; kh < 3; ++kh) {
        int r = h + kh - 1; if (r < 0 || r >= H) continue;
        #pragma unroll
        for (int kw = 0; kw < 3; ++kw) {
            int c = w + kw - 1; if (c < 0 || c >= W) continue;
            s += alpha_t[(b*H + r)*W + c]*cw[kh*3+kw];
        }
    }
    att_out[i] = att_in[i] + s;
}

// ---------------- K3: conv_tan_w OIHW -> bf16 [khw][o][c] ----------------
__global__ __launch_bounds__(256) void k_wtb(const float* src, unsigned short* dst)
{
    int idx = blockIdx.x*256 + threadIdx.x;     // 9*256*256
    int c = idx & 255; int o = (idx >> 8) & 255; int khw = idx >> 16;
    dst[(khw*256 + o)*256 + c] = f2bf(src[(o*256 + c)*9 + khw]);
}

// ---------------- K3b: ua_w [c][d] -> bf16 [d][c] ----------------
__global__ __launch_bounds__(256) void k_uat(const float* src, unsigned short* dst)
{
    int idx = blockIdx.x*256 + threadIdx.x;     // 256*1024
    int c = idx & 1023; int d = idx >> 10;
    dst[d*1024 + c] = f2bf(src[c*256 + d]);
}

// ---------------- K3c: zero et_p (incl. halo) ----------------
__global__ __launch_bounds__(256) void k_zero(int4* p)
{
    p[blockIdx.x*256 + threadIdx.x] = make_int4(0,0,0,0);
}

// ---------------- K4: MFMA GEMM et[m][d] = imgT @ ua_w + fused epilogue -> bf16 NHWC (halo-padded) ----------------
// One block per output row (b,h): M=96, N=256, K=1024 in 16 chunks of 64 (LDS transpose staging).
// Per wave: 6 m-frags x 4 n-frags = 24 acc chains.
__global__ __launch_bounds__(256, 2) void k_et(
    const float* img, const unsigned short* uat, const float* ua_b,
    const float* st1, const float* att_sum, const float* uf_w, const float* uf_b,
    unsigned short* et_p)
{
    int h = blockIdx.x, b = blockIdx.y;
    int t = threadIdx.x;
    int wv = t >> 6, lane = t & 63, q = lane >> 4, ln = lane & 15;
    int n0 = wv*64;
    __shared__ __align__(16) unsigned short a_l[96*72];     // [m][k] stride 72, 13.8 KB

    f32x4 acc[24];                                          // [mf*4 + j]
    #pragma unroll
    for (int i = 0; i < 24; ++i) acc[i] = (f32x4){0.f,0.f,0.f,0.f};

    for (int c0 = 0; c0 < 1024; c0 += 64) {
        __syncthreads();
        #pragma unroll
        for (int i = t; i < 96*8; i += 256) {               // (m, c8): 8 channels each
            int c8 = i / 96; int m = i - c8*96;
            const float* sp = img + (size_t)(b*C + c0 + c8*8)*HW + h*W + m;
            union { short8 v; unsigned short u[8]; } pk;
            #pragma unroll
            for (int jj = 0; jj < 8; ++jj) pk.u[jj] = f2bf(sp[jj*HW]);
            *(short8*)&a_l[m*72 + c8*8] = pk.v;
        }
        __syncthreads();
        #pragma unroll
        for (int cs = 0; cs < 64; cs += 32) {
            short8 av[6];
            #pragma unroll
            for (int mf = 0; mf < 6; ++mf)
                av[mf] = *(const short8*)&a_l[(ln + 16*mf)*72 + cs + q*8];
            #pragma unroll
            for (int j = 0; j < 4; ++j) {
                short8 bv = *(const short8*)&uat[(n0 + j*16 + ln)*1024 + c0 + cs + q*8];
                #pragma unroll
                for (int mf = 0; mf < 6; ++mf)
                    acc[mf*4+j] = __builtin_amdgcn_mfma_f32_16x16x32_bf16(av[mf], bv, acc[mf*4+j], 0, 0, 0);
            }
        }
    }

    // epilogue: + st1 + ua_b + att*uf_w + uf_b, store bf16 NHWC halo-padded
    float att_m[24];
    #pragma unroll
    for (int mf = 0; mf < 6; ++mf)
        #pragma unroll
        for (int r = 0; r < 4; ++r)
            att_m[mf*4+r] = att_sum[(b*H + h)*W + mf*16 + q*4 + r];
    #pragma unroll
    for (int j = 0; j < 4; ++j) {
        int n = n0 + j*16 + ln;
        float s1 = st1[b*256 + n] + ua_b[n];
        float ufw = uf_w[n], ufb = uf_b[n];
        #pragma unroll
        for (int mf = 0; mf < 6; ++mf)
            #pragma unroll
            for (int r = 0; r < 4; ++r) {
                int m = mf*16 + q*4 + r;
                float v = acc[mf*4+j][r] + s1 + att_m[mf*4+r]*ufw + ufb;
                et_p[((size_t)(b*H2 + h + 1)*W2 + (m + 1))*256 + n] = f2bf(v);
            }
    }
}

// ---------------- K5: MFMA conv(3x3,256->256) + BN + tanh + v-dot -> e[b,h,w] ----------------
// One block per output row (b,h): M=96, K=9*256. A = LDS-staged halo patch (c-chunks of 64),
// B = wtb [khw][o][c] streamed from L2. No barriers inside the khw/cs loops.
__global__ __launch_bounds__(256, 2) void k_conv(
    const unsigned short* et_p, const unsigned short* wtb, const float* cb,
    const float* bn_g, const float* bn_b, const float* bn_m, const float* bn_v,
    const float* v_w, const float* v_b, float* e_out)
{
    int h = blockIdx.x, b = blockIdx.y;
    int t = threadIdx.x;
    int wv = t >> 6, lane = t & 63, q = lane >> 4, ln = lane & 15;
    int n0 = wv*64;
    __shared__ __align__(16) unsigned short patch[3*98*72]; // [kh][x][c-chunk] stride 72, 42.3 KB
    __shared__ float lds_red[4][96];

    f32x4 acc[24];                                          // [mf*4 + j]
    #pragma unroll
    for (int i = 0; i < 24; ++i) acc[i] = (f32x4){0.f,0.f,0.f,0.f};

    for (int c0 = 0; c0 < 256; c0 += 64) {
        __syncthreads();
        // stage 3 rows x 98 x-positions x 64 channels: 2352 int4
        for (int i = t; i < 2352; i += 256) {
            int kh = i / 784; int r = i - kh*784; int x = r >> 3; int j = r & 7;
            const int4* src = (const int4*)et_p + ((size_t)(b*H2 + h + kh)*W2 + x)*32 + (c0 >> 3) + j;
            ((int4*)patch)[kh*882 + x*9 + j] = *src;
        }
        __syncthreads();
        #pragma unroll
        for (int kh = 0; kh < 3; ++kh) {
            #pragma unroll
            for (int kw = 0; kw < 3; ++kw) {
                const unsigned short* brow = wtb + ((size_t)((kh*3 + kw)*256 + n0 + ln))*256 + c0 + q*8;
                #pragma unroll
                for (int cs = 0; cs < 64; cs += 32) {
                    short8 av[6];
                    #pragma unroll
                    for (int mf = 0; mf < 6; ++mf)
                        av[mf] = *(const short8*)&patch[kh*7056 + (ln + 16*mf + kw)*72 + cs + q*8];
                    #pragma unroll
                    for (int j = 0; j < 4; ++j) {
                        short8 bv = *(const short8*)(brow + j*4096 + cs);
                        #pragma unroll
                        for (int mf = 0; mf < 6; ++mf)
                            acc[mf*4+j] = __builtin_amdgcn_mfma_f32_16x16x32_bf16(av[mf], bv, acc[mf*4+j], 0, 0, 0);
                    }
                }
            }
        }
    }

    // epilogue: bias + BN + tanh + *v_w, reduce over o (=n)
    float psum[24];                                         // [mf*4 + r]
    #pragma unroll
    for (int i = 0; i < 24; ++i) psum[i] = 0.f;
    #pragma unroll
    for (int j = 0; j < 4; ++j) {
        int o = n0 + j*16 + ln;
        float inv  = bn_g[o]*rsqrtf(bn_v[o] + BN_EPS);
        float mean = bn_m[o], beta = bn_b[o], bias = cb[o], vw = v_w[o];
        #pragma unroll
        for (int mf = 0; mf < 6; ++mf)
            #pragma unroll
            for (int r = 0; r < 4; ++r) {
                float x = (acc[mf*4+j][r] + bias - mean)*inv + beta;
                x = fminf(fmaxf(x, -15.f), 15.f);
                float ex = __expf(2.f*x);
                psum[mf*4+r] += ((ex - 1.f)/(ex + 1.f))*vw;
            }
    }
    #pragma unroll
    for (int s = 1; s < 16; s <<= 1)
        #pragma unroll
        for (int i = 0; i < 24; ++i) psum[i] += __shfl_xor(psum[i], s);
    if (ln == 0) {
        #pragma unroll
        for (int mf = 0; mf < 6; ++mf)
            #pragma unroll
            for (int r = 0; r < 4; ++r)
                lds_red[wv][mf*16 + q*4 + r] = psum[mf*4+r];
    }
    __syncthreads();
    if (t < 96)
        e_out[(b*H + h)*W + t] =
            lds_red[0][t] + lds_red[1][t] + lds_red[2][t] + lds_red[3][t] + v_b[0];
}

// ---------------- K6: masked softmax over (h,w) -> alpha ----------------
__global__ __launch_bounds__(256) void k_softmax(
    const float* e, const int* h_mask, const int* w_mask, float* alpha_out)
{
    int b = blockIdx.x, t = threadIdx.x;
    int hm = h_mask[b], wm = w_mask[b];
    __shared__ float red[256];
    float vals[9];
    float loc = 0.f;
    #pragma unroll
    for (int i = 0; i < 9; ++i) {
        int hw = t + i*256;
        int hh = hw / W, ww = hw % W;
        float v = 0.f;
        if (hh < hm && ww < wm) v = __expf(e[b*HW + hw]);
        vals[i] = v; loc += v;
    }
    red[t] = loc; __syncthreads();
    for (int s = 128; s > 0; s >>= 1) { if (t < s) red[t] += red[t+s]; __syncthreads(); }
    float inv = 1.f/(red[0] + 1e-8f);
    #pragma unroll
    for (int i = 0; i < 9; ++i) alpha_out[b*HW + t + i*256] = vals[i]*inv;
}

// ---------------- K7: ct[b,c] = sum_hw alpha[b,hw]*img[b,c,hw] ----------------
__global__ __launch_bounds__(256) void k_ct(
    const float* alpha, const float* img, float* ct)
{
    int c = blockIdx.x, b = blockIdx.y, t = threadIdx.x;
    const float* ip = img + (size_t)(b*C + c)*HW;
    const float* ap = alpha + b*HW;
    float s = 0.f;
    for (int i = t; i < HW; i += 256) s += ap[i]*ip[i];
    __shared__ float red[256];
    red[t] = s; __syncthreads();
    for (int st = 128; st > 0; st >>= 1) { if (t < st) red[t] += red[t+st]; __syncthreads(); }
    if (t == 0) ct[b*C + c] = red[0];
}

// ---------------- K8: GRU2 + pre (fc2 + emb2 + wc) ----------------
__global__ __launch_bounds__(256) void k_gru2(
    const float* ct, const float* st1, const int* y, const float* emb_table,
    const float* wi, const float* wh, const float* bi, const float* bh,
    const float* fc2_w, const float* fc2_b, const float* emb2_w, const float* emb2_b,
    const float* wc_w, const float* wc_b,
    float* hidden_out, float* pre_out)
{
    int b = blockIdx.x, t = threadIdx.x;
    __shared__ float ct_l[1024], s1_l[256], emb_l[256], st_l[256];
    for (int i = t; i < 1024; i += 256) ct_l[i] = ct[b*C + i];
    s1_l[t]  = st1[b*256 + t];
    emb_l[t] = emb_table[y[b]*EMB + t];
    __syncthreads();
    float ir = bi[t], iz = bi[256+t], in_ = bi[512+t];
    for (int k = 0; k < 1024; ++k) {
        float cv = ct_l[k];
        ir += cv*wi[k*768+t]; iz += cv*wi[k*768+256+t]; in_ += cv*wi[k*768+512+t];
    }
    float hr = bh[t], hz = bh[256+t], hn = bh[512+t];
    for (int k = 0; k < 256; ++k) {
        float hv = s1_l[k];
        hr += hv*wh[k*768+t]; hz += hv*wh[k*768+256+t]; hn += hv*wh[k*768+512+t];
    }
    float r = 1.f/(1.f+__expf(-(ir+hr)));
    float z = 1.f/(1.f+__expf(-(iz+hz)));
    float n = tanhf(in_ + r*hn);
    float s = (1.f - z)*n + z*s1_l[t];
    hidden_out[b*HID + t] = s;
    st_l[t] = s;
    __syncthreads();
    if (t < 128) {
        float acc = fc2_b[t] + emb2_b[t] + wc_b[t];
        for (int k = 0; k < 256; ++k) acc += st_l[k]*fc2_w[k*128+t] + emb_l[k]*emb2_w[k*128+t];
        for (int k = 0; k < 1024; ++k) acc += ct_l[k]*wc_w[k*128+t];
        pre_out[b*128 + t] = acc;
    }
}

// ---------------- K9: logits = pre @ out_w + out_b; log_softmax ----------------
__global__ __launch_bounds__(1024) void k_out(
    const float* pre, const float* out_w, const float* out_b, float* out)
{
    int b = blockIdx.x, t = threadIdx.x;
    __shared__ float pre_l[128];
    __shared__ float red[1024];
    if (t < 128) pre_l[t] = pre[b*128 + t];
    __syncthreads();
    float lg[5];
    float mx = -1e30f;
    #pragma unroll
    for (int i = 0; i < 5; ++i) {
        int j = t + i*1024;
        float a = -1e30f;
        if (j < V) {
            a = out_b[j];
            for (int k = 0; k < 128; ++k) a += pre_l[k]*out_w[k*V + j];
        }
        lg[i] = a; mx = fmaxf(mx, a);
    }
    red[t] = mx; __syncthreads();
    for (int s = 512; s > 0; s >>= 1) { if (t < s) red[t] = fmaxf(red[t], red[t+s]); __syncthreads(); }
    float gmax = red[0]; __syncthreads();
    float se = 0.f;
    #pragma unroll
    for (int i = 0; i < 5; ++i) { int j = t + i*1024; if (j < V) se += __expf(lg[i] - gmax); }
    red[t] = se; __syncthreads();
    for (int s = 512; s > 0; s >>= 1) { if (t < s) red[t] += red[t+s]; __syncthreads(); }
    float lse = logf(red[0]);
    #pragma unroll
    for (int i = 0; i < 5; ++i) { int j = t + i*1024; if (j < V) out[b*V + j] = lg[i] - gmax - lse; }
}

extern "C" void kernel_launch(void* const* d_in, const int* in_sizes, int n_in,
                              void* d_out, int out_size, void* d_ws, size_t ws_size,
                              hipStream_t stream)
{
    const int*   input_y      = (const int*)  d_in[0];
    const float* input_hidden = (const float*)d_in[1];
    const float* img          = (const float*)d_in[2];
    const float* attention    = (const float*)d_in[4];
    const float* alpha_t      = (const float*)d_in[5];
    const int*   h_mask       = (const int*)  d_in[8];
    const int*   w_mask       = (const int*)  d_in[9];
    const float* emb_table    = (const float*)d_in[10];
    const float* gru1_wi      = (const float*)d_in[11];
    const float* gru1_wh      = (const float*)d_in[12];
    const float* gru1_bi      = (const float*)d_in[13];
    const float* gru1_bh      = (const float*)d_in[14];
    const float* fc1_w        = (const float*)d_in[15];
    const float* fc1_b        = (const float*)d_in[16];
    const float* gru2_wi      = (const float*)d_in[17];
    const float* gru2_wh      = (const float*)d_in[18];
    const float* gru2_bi      = (const float*)d_in[19];
    const float* gru2_bh      = (const float*)d_in[20];
    const float* out_w        = (const float*)d_in[21];
    const float* out_b        = (const float*)d_in[22];
    const float* emb2_w       = (const float*)d_in[23];
    const float* emb2_b       = (const float*)d_in[24];
    const float* conv1_w      = (const float*)d_in[25];
    const float* conv1_b      = (const float*)d_in[26];
    const float* conv_tan_w   = (const float*)d_in[27];
    const float* conv_tan_b   = (const float*)d_in[28];
    const float* fc2_w        = (const float*)d_in[29];
    const float* fc2_b        = (const float*)d_in[30];
    const float* ua_w         = (const float*)d_in[31];
    const float* ua_b         = (const float*)d_in[32];
    const float* uf_w         = (const float*)d_in[33];
    const float* uf_b         = (const float*)d_in[34];
    const float* v_w          = (const float*)d_in[35];
    const float* v_b          = (const float*)d_in[36];
    const float* wc_w         = (const float*)d_in[37];
    const float* wc_b         = (const float*)d_in[38];
    const float* bn1_gamma    = (const float*)d_in[39];
    const float* bn1_beta     = (const float*)d_in[40];
    const float* bn1_mean     = (const float*)d_in[41];
    const float* bn1_var      = (const float*)d_in[42];

    float* out = (float*)d_out;
    char*  ws  = (char*)d_ws;
    unsigned short* et_p = (unsigned short*)(ws + WSB_ETP);
    unsigned short* wtb  = (unsigned short*)(ws + WSB_WTB);
    unsigned short* uat  = (unsigned short*)(ws + WSB_UAT);
    float* e_buf = (float*)(ws + WSB_E);
    float* st1   = (float*)(ws + WSB_ST1);
    float* ct    = (float*)(ws + WSB_CT);
    float* pre   = (float*)(ws + WSB_PRE);

    float* out_logits = out + OUT0;
    float* out_hidden = out + OUT1;
    float* out_alpha  = out + OUT2;
    float* out_attsum = out + OUT3;

    k_st1<<<B, 256, 0, stream>>>(input_y, emb_table, input_hidden,
                                 gru1_wi, gru1_wh, gru1_bi, gru1_bh,
                                 fc1_w, fc1_b, st1);
    k_attsum<<<(B*HW)/256, 256, 0, stream>>>(attention, alpha_t, conv1_w, conv1_b, out_attsum);
    k_wtb<<<(9*256*256)/256, 256, 0, stream>>>(conv_tan_w, wtb);
    k_uat<<<(256*1024)/256, 256, 0, stream>>>(ua_w, uat);
    k_zero<<<(B*H2*W2*256/8)/256, 256, 0, stream>>>((int4*)et_p);
    k_et<<<dim3(H, B), 256, 0, stream>>>(img, uat, ua_b, st1, out_attsum,
                                         uf_w, uf_b, et_p);
    k_conv<<<dim3(H, B), 256, 0, stream>>>(et_p, wtb, conv_tan_b,
                                           bn1_gamma, bn1_beta, bn1_mean, bn1_var,
                                           v_w, v_b, e_buf);
    k_softmax<<<B, 256, 0, stream>>>(e_buf, h_mask, w_mask, out_alpha);
    k_ct<<<dim3(C, B), 256, 0, stream>>>(out_alpha, img, ct);
    k_gru2<<<B, 256, 0, stream>>>(ct, st1, input_y, emb_table,
                                  gru2_wi, gru2_wh, gru2_bi, gru2_bh,
                                  fc2_w, fc2_b, emb2_w, emb2_b, wc_w, wc_b,
                                  out_hidden, pre);
    k_out<<<B, 1024, 0, stream>>>(pre, out_w, out_b, out_logits);
}

// Round 4
// 583.085 us; speedup vs baseline: 3.2723x; 1.2543x over previous
//
#include <hip/hip_runtime.h>
#include <hip/hip_bf16.h>

// Problem constants
#define B   16
#define H   24
#define W   96
#define C   1024
#define HID 256
#define V   5000
#define EMB 256
#define HW  (H*W)          // 2304
#define BN_EPS 1e-5f
#define H2  (H+2)          // 26 (halo-padded)
#define W2  (W+2)          // 98

// d_out layout (floats): output[B*V] | hidden[B*HID] | alpha[B*HW] | att_sum[B*HW]
#define OUT0 0
#define OUT1 (B*V)
#define OUT2 (OUT1 + B*HID)
#define OUT3 (OUT2 + B*HW)

// ws layout (bytes, 256-aligned)
#define WSB_ETP   0                      // B*H2*W2*256 bf16 = 20,873,216
#define WSB_WTB   20873216               // 9*256*256 bf16   =  1,179,648
#define WSB_UAT   22052864               // 256*1024 bf16    =    524,288
#define WSB_E     22577152               // B*HW f32         =    147,456
#define WSB_ST1   22724608               // B*256 f32        =     16,384
#define WSB_CT    22740992               // B*1024 f32       =     65,536
#define WSB_PRE   22806528               // B*128 f32        =      8,192
#define WSB_GIGH1 22814720               // B*1536 f32       =     98,304
#define WSB_ST1G  22913024               // B*256 f32        =     16,384
#define WSB_GH2   22929408               // B*896 f32        =     57,344
#define WSB_GI2   22986752               // 4*B*896 f32      =    229,376
#define WSB_STW   23216128               // B*256 f32        =     16,384

typedef __attribute__((ext_vector_type(8))) short short8;
typedef __attribute__((ext_vector_type(4))) float f32x4;

__device__ inline unsigned short f2bf(float f) {
    union { float f; unsigned int u; } v; v.f = f;
    unsigned int r = v.u + 0x7fffu + ((v.u >> 16) & 1u);   // RNE
    return (unsigned short)(r >> 16);
}

// ---------------- K2: 1-ch 3x3 conv on alpha_t + attention_sum -> att_sum ----------------
__global__ __launch_bounds__(256) void k_attsum(
    const float* att_in, const float* alpha_t, const float* cw, const float* cb,
    float* att_out)
{
    int i = blockIdx.x*256 + threadIdx.x;
    int w = i % W; int h = (i / W) % H; int b = i / HW;
    float s = cb[0];
    #pragma unroll
    for (int kh = 0; kh < 3; ++kh) {
        int r = h + kh - 1; if (r < 0 || r >= H) continue;
        #pragma unroll
        for (int kw = 0; kw < 3; ++kw) {
            int c = w + kw - 1; if (c < 0 || c >= W) continue;
            s += alpha_t[(b*H + r)*W + c]*cw[kh*3+kw];
        }
    }
    att_out[i] = att_in[i] + s;
}

// ---------------- K3: conv_tan_w OIHW -> bf16 [khw][o][c] ----------------
__global__ __launch_bounds__(256) void k_wtb(const float* src, unsigned short* dst)
{
    int idx = blockIdx.x*256 + threadIdx.x;     // 9*256*256
    int c = idx & 255; int o = (idx >> 8) & 255; int khw = idx >> 16;
    dst[(khw*256 + o)*256 + c] = f2bf(src[(o*256 + c)*9 + khw]);
}

// ---------------- K3b: ua_w [c][d] -> bf16 [d][c] ----------------
__global__ __launch_bounds__(256) void k_uat(const float* src, unsigned short* dst)
{
    int idx = blockIdx.x*256 + threadIdx.x;     // 256*1024
    int c = idx & 1023; int d = idx >> 10;
    dst[d*1024 + c] = f2bf(src[c*256 + d]);
}

// ---------------- K3c: zero et_p (incl. halo) ----------------
__global__ __launch_bounds__(256) void k_zero(int4* p)
{
    p[blockIdx.x*256 + threadIdx.x] = make_int4(0,0,0,0);
}

// ---------------- GRU1 matmuls: gigh[b][0:768]=emb@wi, [768:1536]=h0@wh ----------------
__global__ __launch_bounds__(256) void k_tail1(
    const int* y, const float* emb_table, const float* h0,
    const float* wi, const float* wh, float* gigh)
{
    int virt = blockIdx.x*16;            // 0..1535
    int t = threadIdx.x;
    bool gi_mode = virt < 768;
    __shared__ float a_l[16*256];
    for (int i = t; i < 4096; i += 256) {
        int b = i >> 8, k = i & 255;
        a_l[i] = gi_mode ? emb_table[y[b]*EMB + k] : h0[b*HID + k];
    }
    __syncthreads();
    int nl = t & 15, b = t >> 4;
    int n = (gi_mode ? virt : virt - 768) + nl;
    const float* wp = gi_mode ? wi : wh;
    float acc = 0.f;
    #pragma unroll 16
    for (int k = 0; k < 256; ++k) acc += a_l[b*256 + k]*wp[k*768 + n];
    gigh[b*1536 + virt + nl] = acc;
}

// ---------------- GRU1 nonlinearity -> st1g ----------------
__global__ __launch_bounds__(256) void k_comb1(
    const float* gigh, const float* h0, const float* bi, const float* bh, float* st1g)
{
    int b = blockIdx.x, t = threadIdx.x;
    const float* g = gigh + b*1536;
    float ir = g[t] + bi[t], iz = g[256+t] + bi[256+t], in_ = g[512+t] + bi[512+t];
    float hr = g[768+t] + bh[t], hz = g[1024+t] + bh[256+t], hn = g[1280+t] + bh[512+t];
    float r = 1.f/(1.f+__expf(-(ir+hr)));
    float z = 1.f/(1.f+__expf(-(iz+hz)));
    float n = tanhf(in_ + r*hn);
    st1g[b*256+t] = (1.f - z)*n + z*h0[b*HID + t];
}

// ---------------- fc1: st1 = st1g @ fc1_w + fc1_b ----------------
__global__ __launch_bounds__(256) void k_fc1s(
    const float* st1g, const float* fc1_w, const float* fc1_b, float* st1)
{
    int n0 = blockIdx.x*16, t = threadIdx.x;
    __shared__ float a_l[16*256];
    for (int i = t; i < 4096; i += 256) a_l[i] = st1g[i];
    __syncthreads();
    int nl = t & 15, b = t >> 4;
    float acc = fc1_b[n0+nl];
    #pragma unroll 16
    for (int k = 0; k < 256; ++k) acc += a_l[b*256+k]*fc1_w[k*256 + n0 + nl];
    st1[b*256 + n0 + nl] = acc;
}

// ---------------- K4: MFMA GEMM et[m][d] = imgT @ ua_w + fused epilogue -> bf16 NHWC (halo-padded) ----------------
__global__ __launch_bounds__(256, 2) void k_et(
    const float* img, const unsigned short* uat, const float* ua_b,
    const float* st1, const float* att_sum, const float* uf_w, const float* uf_b,
    unsigned short* et_p)
{
    int h = blockIdx.x, b = blockIdx.y;
    int t = threadIdx.x;
    int wv = t >> 6, lane = t & 63, q = lane >> 4, ln = lane & 15;
    int n0 = wv*64;
    __shared__ __align__(16) unsigned short a_l[96*72];     // [m][k] stride 72, 13.8 KB

    f32x4 acc[24];
    #pragma unroll
    for (int i = 0; i < 24; ++i) acc[i] = (f32x4){0.f,0.f,0.f,0.f};

    for (int c0 = 0; c0 < 1024; c0 += 64) {
        __syncthreads();
        #pragma unroll
        for (int i = t; i < 96*8; i += 256) {
            int c8 = i / 96; int m = i - c8*96;
            const float* sp = img + (size_t)(b*C + c0 + c8*8)*HW + h*W + m;
            union { short8 v; unsigned short u[8]; } pk;
            #pragma unroll
            for (int jj = 0; jj < 8; ++jj) pk.u[jj] = f2bf(sp[jj*HW]);
            *(short8*)&a_l[m*72 + c8*8] = pk.v;
        }
        __syncthreads();
        #pragma unroll
        for (int cs = 0; cs < 64; cs += 32) {
            short8 av[6];
            #pragma unroll
            for (int mf = 0; mf < 6; ++mf)
                av[mf] = *(const short8*)&a_l[(ln + 16*mf)*72 + cs + q*8];
            #pragma unroll
            for (int j = 0; j < 4; ++j) {
                short8 bv = *(const short8*)&uat[(n0 + j*16 + ln)*1024 + c0 + cs + q*8];
                #pragma unroll
                for (int mf = 0; mf < 6; ++mf)
                    acc[mf*4+j] = __builtin_amdgcn_mfma_f32_16x16x32_bf16(av[mf], bv, acc[mf*4+j], 0, 0, 0);
            }
        }
    }

    float att_m[24];
    #pragma unroll
    for (int mf = 0; mf < 6; ++mf)
        #pragma unroll
        for (int r = 0; r < 4; ++r)
            att_m[mf*4+r] = att_sum[(b*H + h)*W + mf*16 + q*4 + r];
    #pragma unroll
    for (int j = 0; j < 4; ++j) {
        int n = n0 + j*16 + ln;
        float s1 = st1[b*256 + n] + ua_b[n];
        float ufw = uf_w[n], ufb = uf_b[n];
        #pragma unroll
        for (int mf = 0; mf < 6; ++mf)
            #pragma unroll
            for (int r = 0; r < 4; ++r) {
                int m = mf*16 + q*4 + r;
                float v = acc[mf*4+j][r] + s1 + att_m[mf*4+r]*ufw + ufb;
                et_p[((size_t)(b*H2 + h + 1)*W2 + (m + 1))*256 + n] = f2bf(v);
            }
    }
}

// ---------------- K5: MFMA conv(3x3,256->256) + BN + tanh + v-dot -> e[b,h,w] ----------------
__global__ __launch_bounds__(256, 2) void k_conv(
    const unsigned short* et_p, const unsigned short* wtb, const float* cb,
    const float* bn_g, const float* bn_b, const float* bn_m, const float* bn_v,
    const float* v_w, const float* v_b, float* e_out)
{
    int h = blockIdx.x, b = blockIdx.y;
    int t = threadIdx.x;
    int wv = t >> 6, lane = t & 63, q = lane >> 4, ln = lane & 15;
    int n0 = wv*64;
    __shared__ __align__(16) unsigned short patch[3*98*72]; // 42.3 KB
    __shared__ float lds_red[4][96];

    f32x4 acc[24];
    #pragma unroll
    for (int i = 0; i < 24; ++i) acc[i] = (f32x4){0.f,0.f,0.f,0.f};

    for (int c0 = 0; c0 < 256; c0 += 64) {
        __syncthreads();
        for (int i = t; i < 2352; i += 256) {
            int kh = i / 784; int r = i - kh*784; int x = r >> 3; int j = r & 7;
            const int4* src = (const int4*)et_p + ((size_t)(b*H2 + h + kh)*W2 + x)*32 + (c0 >> 3) + j;
            ((int4*)patch)[kh*882 + x*9 + j] = *src;
        }
        __syncthreads();
        #pragma unroll
        for (int kh = 0; kh < 3; ++kh) {
            #pragma unroll
            for (int kw = 0; kw < 3; ++kw) {
                const unsigned short* brow = wtb + ((size_t)((kh*3 + kw)*256 + n0 + ln))*256 + c0 + q*8;
                #pragma unroll
                for (int cs = 0; cs < 64; cs += 32) {
                    short8 av[6];
                    #pragma unroll
                    for (int mf = 0; mf < 6; ++mf)
                        av[mf] = *(const short8*)&patch[kh*7056 + (ln + 16*mf + kw)*72 + cs + q*8];
                    #pragma unroll
                    for (int j = 0; j < 4; ++j) {
                        short8 bv = *(const short8*)(brow + j*4096 + cs);
                        #pragma unroll
                        for (int mf = 0; mf < 6; ++mf)
                            acc[mf*4+j] = __builtin_amdgcn_mfma_f32_16x16x32_bf16(av[mf], bv, acc[mf*4+j], 0, 0, 0);
                    }
                }
            }
        }
    }

    float psum[24];
    #pragma unroll
    for (int i = 0; i < 24; ++i) psum[i] = 0.f;
    #pragma unroll
    for (int j = 0; j < 4; ++j) {
        int o = n0 + j*16 + ln;
        float inv  = bn_g[o]*rsqrtf(bn_v[o] + BN_EPS);
        float mean = bn_m[o], beta = bn_b[o], bias = cb[o], vw = v_w[o];
        #pragma unroll
        for (int mf = 0; mf < 6; ++mf)
            #pragma unroll
            for (int r = 0; r < 4; ++r) {
                float x = (acc[mf*4+j][r] + bias - mean)*inv + beta;
                x = fminf(fmaxf(x, -15.f), 15.f);
                float ex = __expf(2.f*x);
                psum[mf*4+r] += ((ex - 1.f)/(ex + 1.f))*vw;
            }
    }
    #pragma unroll
    for (int s = 1; s < 16; s <<= 1)
        #pragma unroll
        for (int i = 0; i < 24; ++i) psum[i] += __shfl_xor(psum[i], s);
    if (ln == 0) {
        #pragma unroll
        for (int mf = 0; mf < 6; ++mf)
            #pragma unroll
            for (int r = 0; r < 4; ++r)
                lds_red[wv][mf*16 + q*4 + r] = psum[mf*4+r];
    }
    __syncthreads();
    if (t < 96)
        e_out[(b*H + h)*W + t] =
            lds_red[0][t] + lds_red[1][t] + lds_red[2][t] + lds_red[3][t] + v_b[0];
}

// ---------------- K6: masked softmax over (h,w) -> alpha ----------------
__global__ __launch_bounds__(256) void k_softmax(
    const float* e, const int* h_mask, const int* w_mask, float* alpha_out)
{
    int b = blockIdx.x, t = threadIdx.x;
    int hm = h_mask[b], wm = w_mask[b];
    __shared__ float red[256];
    float vals[9];
    float loc = 0.f;
    #pragma unroll
    for (int i = 0; i < 9; ++i) {
        int hw = t + i*256;
        int hh = hw / W, ww = hw % W;
        float v = 0.f;
        if (hh < hm && ww < wm) v = __expf(e[b*HW + hw]);
        vals[i] = v; loc += v;
    }
    red[t] = loc; __syncthreads();
    for (int s = 128; s > 0; s >>= 1) { if (t < s) red[t] += red[t+s]; __syncthreads(); }
    float inv = 1.f/(red[0] + 1e-8f);
    #pragma unroll
    for (int i = 0; i < 9; ++i) alpha_out[b*HW + t + i*256] = vals[i]*inv;
}

// ---------------- K7: ct[b,c] = sum_hw alpha[b,hw]*img[b,c,hw] ----------------
__global__ __launch_bounds__(256) void k_ct(
    const float* alpha, const float* img, float* ct)
{
    int c = blockIdx.x, b = blockIdx.y, t = threadIdx.x;
    const float* ip = img + (size_t)(b*C + c)*HW;
    const float* ap = alpha + b*HW;
    float s = 0.f;
    for (int i = t; i < HW; i += 256) s += ap[i]*ip[i];
    __shared__ float red[256];
    red[t] = s; __syncthreads();
    for (int st = 128; st > 0; st >>= 1) { if (t < st) red[t] += red[t+st]; __syncthreads(); }
    if (t == 0) ct[b*C + c] = red[0];
}

// ---------------- GRU2 h-side + pemb: gh2[b][0:768]=st1@wh, [768:896]=emb@emb2_w ----------------
__global__ __launch_bounds__(256) void k_gh2pe(
    const float* st1, const int* y, const float* emb_table,
    const float* wh, const float* emb2_w, float* gh2)
{
    int virt = blockIdx.x*16, t = threadIdx.x;
    bool ghm = virt < 768;
    __shared__ float a_l[16*256];
    for (int i = t; i < 4096; i += 256) {
        int b = i >> 8, k = i & 255;
        a_l[i] = ghm ? st1[b*256 + k] : emb_table[y[b]*EMB + k];
    }
    __syncthreads();
    int nl = t & 15, b = t >> 4;
    float acc = 0.f;
    if (ghm) {
        int n = virt + nl;
        #pragma unroll 16
        for (int k = 0; k < 256; ++k) acc += a_l[b*256+k]*wh[k*768 + n];
    } else {
        int n = virt - 768 + nl;
        #pragma unroll 16
        for (int k = 0; k < 256; ++k) acc += a_l[b*256+k]*emb2_w[k*128 + n];
    }
    gh2[b*896 + virt + nl] = acc;
}

// ---------------- GRU2 i-side + wc (split-K): gi2p[ks][b][0:768]=ct@wi, [768:896]=ct@wc_w ----------------
__global__ __launch_bounds__(256) void k_gi2(
    const float* ct, const float* wi, const float* wc_w, float* gi2p)
{
    int virt = blockIdx.x*16, ks = blockIdx.y, t = threadIdx.x;
    int k0 = ks*256;
    __shared__ float a_l[16*256];
    for (int i = t; i < 4096; i += 256) {
        int b = i >> 8, k = i & 255;
        a_l[i] = ct[b*1024 + k0 + k];
    }
    __syncthreads();
    int nl = t & 15, b = t >> 4;
    float acc = 0.f;
    if (virt < 768) {
        int n = virt + nl;
        #pragma unroll 16
        for (int k = 0; k < 256; ++k) acc += a_l[b*256+k]*wi[(k0+k)*768 + n];
    } else {
        int n = virt - 768 + nl;
        #pragma unroll 16
        for (int k = 0; k < 256; ++k) acc += a_l[b*256+k]*wc_w[(k0+k)*128 + n];
    }
    gi2p[(ks*16 + b)*896 + virt + nl] = acc;
}

// ---------------- GRU2 nonlinearity -> st (+hidden out) ----------------
__global__ __launch_bounds__(256) void k_comb2(
    const float* gi2p, const float* gh2, const float* st1,
    const float* bi, const float* bh, float* hidden_out, float* st_ws)
{
    int b = blockIdx.x, t = threadIdx.x;
    float ir = bi[t], iz = bi[256+t], in_ = bi[512+t];
    #pragma unroll
    for (int ks = 0; ks < 4; ++ks) {
        const float* g = gi2p + (ks*16 + b)*896;
        ir += g[t]; iz += g[256+t]; in_ += g[512+t];
    }
    const float* gh = gh2 + b*896;
    float hr = gh[t] + bh[t], hz = gh[256+t] + bh[256+t], hn = gh[512+t] + bh[512+t];
    float h = st1[b*256+t];
    float r = 1.f/(1.f+__expf(-(ir+hr)));
    float z = 1.f/(1.f+__expf(-(iz+hz)));
    float n = tanhf(in_ + r*hn);
    float s = (1.f - z)*n + z*h;
    hidden_out[b*HID + t] = s;
    st_ws[b*256 + t] = s;
}

// ---------------- pre = st@fc2_w + fc2_b + pemb + emb2_b + wcp + wc_b ----------------
__global__ __launch_bounds__(256) void k_fc2s(
    const float* st_ws, const float* fc2_w, const float* fc2_b,
    const float* gh2, const float* emb2_b, const float* gi2p,
    const float* wc_b, float* pre)
{
    int n0 = blockIdx.x*16, t = threadIdx.x;
    __shared__ float a_l[16*256];
    for (int i = t; i < 4096; i += 256) a_l[i] = st_ws[i];
    __syncthreads();
    int nl = t & 15, b = t >> 4;
    int n = n0 + nl;
    float acc = fc2_b[n] + emb2_b[n] + wc_b[n] + gh2[b*896 + 768 + n];
    #pragma unroll
    for (int ks = 0; ks < 4; ++ks) acc += gi2p[(ks*16 + b)*896 + 768 + n];
    #pragma unroll 16
    for (int k = 0; k < 256; ++k) acc += a_l[b*256+k]*fc2_w[k*128 + n];
    pre[b*128 + n] = acc;
}

// ---------------- logits (raw) = pre @ out_w + out_b ----------------
__global__ __launch_bounds__(256) void k_logits(
    const float* pre, const float* out_w, const float* out_b, float* out)
{
    int j0 = blockIdx.x*64, t = threadIdx.x;
    __shared__ float pre_l[16*128];
    for (int i = t; i < 2048; i += 256) pre_l[i] = pre[i];
    __syncthreads();
    int jl = t & 63, bg = t >> 6;
    int j = j0 + jl;
    if (j >= V) return;
    float acc0=0.f, acc1=0.f, acc2=0.f, acc3=0.f;
    const float* pl = pre_l + bg*4*128;
    #pragma unroll 8
    for (int k = 0; k < 128; ++k) {
        float wv = out_w[k*V + j];
        acc0 += pl[k]*wv; acc1 += pl[128+k]*wv; acc2 += pl[256+k]*wv; acc3 += pl[384+k]*wv;
    }
    float ob = out_b[j];
    out[(bg*4+0)*V + j] = acc0 + ob;
    out[(bg*4+1)*V + j] = acc1 + ob;
    out[(bg*4+2)*V + j] = acc2 + ob;
    out[(bg*4+3)*V + j] = acc3 + ob;
}

// ---------------- in-place log_softmax over V per batch ----------------
__global__ __launch_bounds__(1024) void k_lsm(float* out)
{
    int b = blockIdx.x, t = threadIdx.x;
    __shared__ float red[1024];
    float lg[5]; float mx = -1e30f;
    #pragma unroll
    for (int i = 0; i < 5; ++i) {
        int j = t + i*1024;
        lg[i] = (j < V) ? out[b*V + j] : -1e30f;
        mx = fmaxf(mx, lg[i]);
    }
    red[t] = mx; __syncthreads();
    for (int s = 512; s > 0; s >>= 1) { if (t < s) red[t] = fmaxf(red[t], red[t+s]); __syncthreads(); }
    float gmax = red[0]; __syncthreads();
    float se = 0.f;
    #pragma unroll
    for (int i = 0; i < 5; ++i) { int j = t + i*1024; if (j < V) se += __expf(lg[i] - gmax); }
    red[t] = se; __syncthreads();
    for (int s = 512; s > 0; s >>= 1) { if (t < s) red[t] += red[t+s]; __syncthreads(); }
    float lse = logf(red[0]);
    #pragma unroll
    for (int i = 0; i < 5; ++i) { int j = t + i*1024; if (j < V) out[b*V + j] = lg[i] - gmax - lse; }
}

extern "C" void kernel_launch(void* const* d_in, const int* in_sizes, int n_in,
                              void* d_out, int out_size, void* d_ws, size_t ws_size,
                              hipStream_t stream)
{
    const int*   input_y      = (const int*)  d_in[0];
    const float* input_hidden = (const float*)d_in[1];
    const float* img          = (const float*)d_in[2];
    const float* attention    = (const float*)d_in[4];
    const float* alpha_t      = (const float*)d_in[5];
    const int*   h_mask       = (const int*)  d_in[8];
    const int*   w_mask       = (const int*)  d_in[9];
    const float* emb_table    = (const float*)d_in[10];
    const float* gru1_wi      = (const float*)d_in[11];
    const float* gru1_wh      = (const float*)d_in[12];
    const float* gru1_bi      = (const float*)d_in[13];
    const float* gru1_bh      = (const float*)d_in[14];
    const float* fc1_w        = (const float*)d_in[15];
    const float* fc1_b        = (const float*)d_in[16];
    const float* gru2_wi      = (const float*)d_in[17];
    const float* gru2_wh      = (const float*)d_in[18];
    const float* gru2_bi      = (const float*)d_in[19];
    const float* gru2_bh      = (const float*)d_in[20];
    const float* out_w        = (const float*)d_in[21];
    const float* out_b        = (const float*)d_in[22];
    const float* emb2_w       = (const float*)d_in[23];
    const float* emb2_b       = (const float*)d_in[24];
    const float* conv1_w      = (const float*)d_in[25];
    const float* conv1_b      = (const float*)d_in[26];
    const float* conv_tan_w   = (const float*)d_in[27];
    const float* conv_tan_b   = (const float*)d_in[28];
    const float* fc2_w        = (const float*)d_in[29];
    const float* fc2_b        = (const float*)d_in[30];
    const float* ua_w         = (const float*)d_in[31];
    const float* ua_b         = (const float*)d_in[32];
    const float* uf_w         = (const float*)d_in[33];
    const float* uf_b         = (const float*)d_in[34];
    const float* v_w          = (const float*)d_in[35];
    const float* v_b          = (const float*)d_in[36];
    const float* wc_w         = (const float*)d_in[37];
    const float* wc_b         = (const float*)d_in[38];
    const float* bn1_gamma    = (const float*)d_in[39];
    const float* bn1_beta     = (const float*)d_in[40];
    const float* bn1_mean     = (const float*)d_in[41];
    const float* bn1_var      = (const float*)d_in[42];

    float* out = (float*)d_out;
    char*  ws  = (char*)d_ws;
    unsigned short* et_p = (unsigned short*)(ws + WSB_ETP);
    unsigned short* wtb  = (unsigned short*)(ws + WSB_WTB);
    unsigned short* uat  = (unsigned short*)(ws + WSB_UAT);
    float* e_buf = (float*)(ws + WSB_E);
    float* st1   = (float*)(ws + WSB_ST1);
    float* ct    = (float*)(ws + WSB_CT);
    float* pre   = (float*)(ws + WSB_PRE);
    float* gigh1 = (float*)(ws + WSB_GIGH1);
    float* st1g  = (float*)(ws + WSB_ST1G);
    float* gh2   = (float*)(ws + WSB_GH2);
    float* gi2p  = (float*)(ws + WSB_GI2);
    float* st_w  = (float*)(ws + WSB_STW);

    float* out_logits = out + OUT0;
    float* out_hidden = out + OUT1;
    float* out_alpha  = out + OUT2;
    float* out_attsum = out + OUT3;

    k_tail1<<<96, 256, 0, stream>>>(input_y, emb_table, input_hidden,
                                    gru1_wi, gru1_wh, gigh1);
    k_comb1<<<B, 256, 0, stream>>>(gigh1, input_hidden, gru1_bi, gru1_bh, st1g);
    k_fc1s<<<16, 256, 0, stream>>>(st1g, fc1_w, fc1_b, st1);
    k_attsum<<<(B*HW)/256, 256, 0, stream>>>(attention, alpha_t, conv1_w, conv1_b, out_attsum);
    k_wtb<<<(9*256*256)/256, 256, 0, stream>>>(conv_tan_w, wtb);
    k_uat<<<(256*1024)/256, 256, 0, stream>>>(ua_w, uat);
    k_zero<<<(B*H2*W2*256/8)/256, 256, 0, stream>>>((int4*)et_p);
    k_et<<<dim3(H, B), 256, 0, stream>>>(img, uat, ua_b, st1, out_attsum,
                                         uf_w, uf_b, et_p);
    k_conv<<<dim3(H, B), 256, 0, stream>>>(et_p, wtb, conv_tan_b,
                                           bn1_gamma, bn1_beta, bn1_mean, bn1_var,
                                           v_w, v_b, e_buf);
    k_softmax<<<B, 256, 0, stream>>>(e_buf, h_mask, w_mask, out_alpha);
    k_ct<<<dim3(C, B), 256, 0, stream>>>(out_alpha, img, ct);
    k_gh2pe<<<56, 256, 0, stream>>>(st1, input_y, emb_table, gru2_wh, emb2_w, gh2);
    k_gi2<<<dim3(56, 4), 256, 0, stream>>>(ct, gru2_wi, wc_w, gi2p);
    k_comb2<<<B, 256, 0, stream>>>(gi2p, gh2, st1, gru2_bi, gru2_bh, out_hidden, st_w);
    k_fc2s<<<8, 256, 0, stream>>>(st_w, fc2_w, fc2_b, gh2, emb2_b, gi2p, wc_b, pre);
    k_logits<<<(V + 63)/64, 256, 0, stream>>>(pre, out_w, out_b, out_logits);
    k_lsm<<<B, 1024, 0, stream>>>(out_logits);
}